// Round 9
// baseline (910.701 us; speedup 1.0000x reference)
//
#include <hip/hip_runtime.h>
#include <hip/hip_bf16.h>
#include <cmath>

#define N_NODES 50000
#define IN_F 64
#define L 128
#define STEPS 3
#define T_TYPES 4
#define E_EDGES 800000
#define NB4 (N_NODES * 4)

typedef __attribute__((ext_vector_type(8))) __bf16 bf16x8_t;
typedef __attribute__((ext_vector_type(4))) float f32x4;

__device__ inline float bf2f(ushort u) {
  union { uint i; float f; } v; v.i = ((uint)u) << 16; return v.f;
}
__device__ inline ushort f2bf(float f) {
  union { float f; uint u; } v; v.f = f;
  uint u = v.u;
  u += 0x7fffu + ((u >> 16) & 1u);  // RNE
  return (ushort)(u >> 16);
}

// ---------------- fp32 tiled matmul for x0 (K=64), writes bf16 ----------------
#define BN 64
#define BO 64
#define BK 16
__global__ __launch_bounds__(256) void matmul_x0(
    const float* __restrict__ A, const float* __restrict__ W,
    const float* __restrict__ bias, ushort* __restrict__ Cb,
    int N, int K, int OUT)
{
  __shared__ float As[BN][BK + 1];
  __shared__ float Ws[BO][BK + 1];
  const int tid = threadIdx.x;
  const int n_base = blockIdx.x * BN;
  const int o_base = blockIdx.y * BO;
  const int tx = tid & 15, ty = tid >> 4;
  const int n0 = ty * 4, o0 = tx * 4;
  const int lr = tid >> 2, lc = (tid & 3) * 4;
  float acc[4][4] = {{0.f, 0.f, 0.f, 0.f}};
  for (int kc = 0; kc < K; kc += BK) {
    int gn = n_base + lr;
    float4 av = make_float4(0.f, 0.f, 0.f, 0.f);
    if (gn < N) av = *(const float4*)(A + (size_t)gn * K + kc + lc);
    As[lr][lc + 0] = av.x; As[lr][lc + 1] = av.y;
    As[lr][lc + 2] = av.z; As[lr][lc + 3] = av.w;
    float4 wv = *(const float4*)(W + (size_t)(o_base + lr) * K + kc + lc);
    Ws[lr][lc + 0] = wv.x; Ws[lr][lc + 1] = wv.y;
    Ws[lr][lc + 2] = wv.z; Ws[lr][lc + 3] = wv.w;
    __syncthreads();
#pragma unroll
    for (int kk = 0; kk < BK; ++kk) {
      float a[4], w[4];
#pragma unroll
      for (int i = 0; i < 4; ++i) a[i] = As[n0 + i][kk];
#pragma unroll
      for (int j = 0; j < 4; ++j) w[j] = Ws[o0 + j][kk];
#pragma unroll
      for (int i = 0; i < 4; ++i)
#pragma unroll
        for (int j = 0; j < 4; ++j) acc[i][j] += a[i] * w[j];
    }
    __syncthreads();
  }
#pragma unroll
  for (int i = 0; i < 4; ++i) {
    int gn = n_base + n0 + i;
    if (gn >= N) continue;
    int o = o_base + o0;
    float v0 = fmaxf(acc[i][0] + bias[o + 0], 0.f);
    float v1 = fmaxf(acc[i][1] + bias[o + 1], 0.f);
    float v2 = fmaxf(acc[i][2] + bias[o + 2], 0.f);
    float v3 = fmaxf(acc[i][3] + bias[o + 3], 0.f);
    uint2 pk;
    pk.x = (uint)f2bf(v0) | ((uint)f2bf(v1) << 16);
    pk.y = (uint)f2bf(v2) | ((uint)f2bf(v3) << 16);
    *(uint2*)(Cb + (size_t)gn * OUT + o) = pk;
  }
}

// ---------------- MFMA GEMM (K=128): KIND 0: bf16+bias (gh). KIND 4: heads mu/lv f32 ----------------
template<int OUT, int KIND>
__global__ __launch_bounds__(256) void gemm_mfma(
    const ushort* __restrict__ A, const ushort* __restrict__ W,
    const float* __restrict__ bias, float* __restrict__ Cf,
    ushort* __restrict__ Cb, const float* __restrict__ bias2,
    float* __restrict__ Cf2, int N)
{
  constexpr int K = 128;
  constexpr int NOT = OUT / 16;
  const int lane = threadIdx.x & 63;
  const int wave = threadIdx.x >> 6;
  const int r = lane & 15;
  const int kg = lane >> 4;
  const int row0 = (blockIdx.x * 8 + wave * 2) * 16;
  if (row0 >= N) return;

  int arow0 = row0 + r;          if (arow0 >= N) arow0 = N - 1;
  int arow1 = row0 + 16 + r;     if (arow1 >= N) arow1 = N - 1;
  const ushort* ap0 = A + (size_t)arow0 * K + kg * 8;
  const ushort* ap1 = A + (size_t)arow1 * K + kg * 8;
  const ushort* wp = W + (size_t)r * K + kg * 8;

  bf16x8_t af[2][4];
#pragma unroll
  for (int kt = 0; kt < 4; ++kt) {
    af[0][kt] = *(const bf16x8_t*)(ap0 + kt * 32);
    af[1][kt] = *(const bf16x8_t*)(ap1 + kt * 32);
  }
#pragma unroll
  for (int otp = 0; otp < NOT / 2; ++otp) {
    bf16x8_t w0[4], w1[4];
#pragma unroll
    for (int kt = 0; kt < 4; ++kt) {
      w0[kt] = *(const bf16x8_t*)(wp + (size_t)(2 * otp) * 16 * K + kt * 32);
      w1[kt] = *(const bf16x8_t*)(wp + (size_t)(2 * otp + 1) * 16 * K + kt * 32);
    }
    f32x4 acc[2][2] = {{{0.f,0.f,0.f,0.f},{0.f,0.f,0.f,0.f}},
                       {{0.f,0.f,0.f,0.f},{0.f,0.f,0.f,0.f}}};
#pragma unroll
    for (int kt = 0; kt < 4; ++kt) {
#pragma unroll
      for (int rt = 0; rt < 2; ++rt) {
        acc[rt][0] = __builtin_amdgcn_mfma_f32_16x16x32_bf16(af[rt][kt], w0[kt], acc[rt][0], 0, 0, 0);
        acc[rt][1] = __builtin_amdgcn_mfma_f32_16x16x32_bf16(af[rt][kt], w1[kt], acc[rt][1], 0, 0, 0);
      }
    }
#pragma unroll
    for (int rt = 0; rt < 2; ++rt) {
#pragma unroll
      for (int oi = 0; oi < 2; ++oi) {
        int o = (2 * otp + oi) * 16 + r;
#pragma unroll
        for (int reg = 0; reg < 4; ++reg) {
          int n = row0 + rt * 16 + kg * 4 + reg;
          if (n >= N) continue;
          float v = acc[rt][oi][reg];
          if constexpr (KIND == 0) {
            Cb[(size_t)n * OUT + o] = f2bf(v + bias[o]);
          } else {
            if (o < 128) Cf[(size_t)n * 128 + o] = v + bias[o];
            else Cf2[(size_t)n * 128 + (o - 128)] = v + bias2[o - 128];
          }
        }
      }
    }
  }
}

// ---------------- fused GRU GEMM: gi = S @ Wcomb^T (K=512), barrier-free, W from L2 ----------------
// Block = 64 rows x 384 cols; wave w owns col-quarter (tiles gt = w*6..w*6+5 = 2 gate-triples)
// across all 4 row-tiles. No LDS, no barriers; 48 MFMAs per K-chunk per wave.
__global__ __launch_bounds__(256) void gru_gemm(
    const ushort* __restrict__ S, const ushort* __restrict__ Wc,
    const float* __restrict__ bias, const ushort* __restrict__ ghb,
    const ushort* __restrict__ x0b, ushort* __restrict__ m_out, int N)
{
  const int lane = threadIdx.x & 63;
  const int wave = threadIdx.x >> 6;   // column quarter
  const int r = lane & 15;
  const int kg = lane >> 4;
  const int row0 = blockIdx.x * 64;

  const ushort* ap0;
  const ushort* ap1;
  const ushort* ap2;
  const ushort* ap3;
  {
    int a0 = row0 + r;        if (a0 >= N) a0 = N - 1;
    int a1 = row0 + 16 + r;   if (a1 >= N) a1 = N - 1;
    int a2 = row0 + 32 + r;   if (a2 >= N) a2 = N - 1;
    int a3 = row0 + 48 + r;   if (a3 >= N) a3 = N - 1;
    ap0 = S + (size_t)a0 * 512 + kg * 8;
    ap1 = S + (size_t)a1 * 512 + kg * 8;
    ap2 = S + (size_t)a2 * 512 + kg * 8;
    ap3 = S + (size_t)a3 * 512 + kg * 8;
  }
  const ushort* wp = Wc + ((size_t)(wave * 96 + r)) * 512 + kg * 8;

  f32x4 acc[4][6];
#pragma unroll
  for (int rt = 0; rt < 4; ++rt)
#pragma unroll
    for (int ot = 0; ot < 6; ++ot) acc[rt][ot] = {0.f, 0.f, 0.f, 0.f};

#pragma unroll 2
  for (int c = 0; c < 8; ++c) {
#pragma unroll
    for (int kk = 0; kk < 2; ++kk) {
      const int ko = c * 64 + kk * 32;
      bf16x8_t a0 = *(const bf16x8_t*)(ap0 + ko);
      bf16x8_t a1 = *(const bf16x8_t*)(ap1 + ko);
      bf16x8_t a2 = *(const bf16x8_t*)(ap2 + ko);
      bf16x8_t a3 = *(const bf16x8_t*)(ap3 + ko);
#pragma unroll
      for (int ot = 0; ot < 6; ++ot) {
        bf16x8_t w = *(const bf16x8_t*)(wp + (size_t)ot * 16 * 512 + ko);
        acc[0][ot] = __builtin_amdgcn_mfma_f32_16x16x32_bf16(a0, w, acc[0][ot], 0, 0, 0);
        acc[1][ot] = __builtin_amdgcn_mfma_f32_16x16x32_bf16(a1, w, acc[1][ot], 0, 0, 0);
        acc[2][ot] = __builtin_amdgcn_mfma_f32_16x16x32_bf16(a2, w, acc[2][ot], 0, 0, 0);
        acc[3][ot] = __builtin_amdgcn_mfma_f32_16x16x32_bf16(a3, w, acc[3][ot], 0, 0, 0);
      }
    }
  }

  // epilogue: wave owns gate-triples jg = wave*2 + jl (jl=0,1); tile ot = jl*3 + gate
#pragma unroll
  for (int jl = 0; jl < 2; ++jl) {
    int j = (wave * 2 + jl) * 16 + r;
    float br = bias[j], bz = bias[128 + j], bn = bias[256 + j];
#pragma unroll
    for (int rt = 0; rt < 4; ++rt) {
#pragma unroll
      for (int reg = 0; reg < 4; ++reg) {
        int n = row0 + rt * 16 + kg * 4 + reg;
        if (n >= N) continue;
        const ushort* ghp = ghb + (size_t)n * 384;
        float gir = acc[rt][jl * 3 + 0][reg] + br + bf2f(ghp[j]);
        float giz = acc[rt][jl * 3 + 1][reg] + bz + bf2f(ghp[128 + j]);
        float ghn = bf2f(ghp[256 + j]);
        float rr = 1.f / (1.f + expf(-gir));
        float zz = 1.f / (1.f + expf(-giz));
        float nn = tanhf(acc[rt][jl * 3 + 2][reg] + bn + rr * ghn);
        float x0v = bf2f(x0b[(size_t)n * 128 + j]);
        float h = (1.f - zz) * nn + zz * x0v;
        m_out[(size_t)n * 128 + j] = f2bf(fmaxf(h, 0.f));
      }
    }
  }
}

// ---------------- weight conversion: w_hh + heads -> bf16 ----------------
#define WOFF_WHH 0
#define WOFF_HEADS 49152
#define WTOT 81920

__global__ __launch_bounds__(256) void convert_weights(
    const float* __restrict__ w_hh, const float* __restrict__ mu_w,
    const float* __restrict__ lv_w, ushort* __restrict__ wsb)
{
  int i = blockIdx.x * 256 + threadIdx.x;
  if (i >= WTOT) return;
  float v;
  if (i < WOFF_HEADS) v = w_hh[i];
  else {
    int k = i - WOFF_HEADS;
    v = (k < 16384) ? mu_w[k] : lv_w[k - 16384];
  }
  wsb[i] = f2bf(v);
}

// Wcomb[s][o'][t*128+j] = 2 * sum_i w_ih[o,i] * gnn_w[s,t,i,j]
// row permutation: o' = jg*48 + g*16 + rr  <->  o = g*128 + jg*16 + rr
__global__ __launch_bounds__(256) void make_wcomb(
    const float* __restrict__ w_ih, const float* __restrict__ gnn_w,
    ushort* __restrict__ wc)
{
  int idx = blockIdx.x * 256 + threadIdx.x;
  if (idx >= STEPS * 384 * 512) return;
  int s = idx / (384 * 512);
  int rem = idx % (384 * 512);
  int op = rem >> 9;
  int col = rem & 511;
  int jg = op / 48;
  int rem2 = op % 48;
  int g = rem2 / 16;
  int rr = rem2 % 16;
  int o = g * 128 + jg * 16 + rr;
  int t = col >> 7, jj = col & 127;
  const float* wi = w_ih + (size_t)o * 128;
  const float* gp = gnn_w + ((size_t)(s * 4 + t) * 128) * 128 + jj;
  float acc = 0.f;
#pragma unroll 8
  for (int i = 0; i < 128; ++i) acc += wi[i] * gp[(size_t)i * 128];
  wc[idx] = f2bf(2.f * acc);
}

// ---------------- CSR build keyed by (dst*4 + type) ----------------
__global__ __launch_bounds__(256) void hist_key(
    const int* __restrict__ ei, const float* __restrict__ ea,
    int* __restrict__ counts, int* __restrict__ ekey)
{
  int e = blockIdx.x * 256 + threadIdx.x;
  if (e >= E_EDGES) return;
  const float* a = ea + (size_t)e * T_TYPES;
  float bv = a[0]; int bi = 0;
#pragma unroll
  for (int t = 1; t < T_TYPES; ++t) {
    float v = a[t];
    if (v > bv) { bv = v; bi = t; }
  }
  int key = ei[E_EDGES + e] * 4 + bi;
  ekey[e] = key;
  atomicAdd(&counts[key], 1);
}

__global__ __launch_bounds__(1024) void scan_block(
    const int* __restrict__ counts, int* __restrict__ excl,
    int* __restrict__ bsum, int n)
{
  __shared__ int ls[1024];
  const int tid = threadIdx.x;
  const int i = blockIdx.x * 1024 + tid;
  int v = (i < n) ? counts[i] : 0;
  ls[tid] = v;
  __syncthreads();
  for (int off = 1; off < 1024; off <<= 1) {
    int t = (tid >= off) ? ls[tid - off] : 0;
    __syncthreads();
    ls[tid] += t;
    __syncthreads();
  }
  if (i < n) excl[i] = ls[tid] - v;
  if (tid == 1023) bsum[blockIdx.x] = ls[1023];
}

__global__ __launch_bounds__(256) void scan_bsums(
    const int* __restrict__ bsum, int* __restrict__ boff, int nb)
{
  __shared__ int ls[256];
  const int tid = threadIdx.x;
  int v = (tid < nb) ? bsum[tid] : 0;
  ls[tid] = v;
  __syncthreads();
  for (int off = 1; off < 256; off <<= 1) {
    int t = (tid >= off) ? ls[tid - off] : 0;
    __syncthreads();
    ls[tid] += t;
    __syncthreads();
  }
  if (tid < nb) boff[tid] = ls[tid] - v;
}

__global__ __launch_bounds__(1024) void scan_final(
    const int* __restrict__ excl, const int* __restrict__ boff,
    int* __restrict__ offsets, int* __restrict__ cursor, int n)
{
  int i = blockIdx.x * 1024 + threadIdx.x;
  if (i == 0) { offsets[n] = E_EDGES; }
  if (i >= n) return;
  int o = excl[i] + boff[blockIdx.x];
  offsets[i] = o;
  cursor[i] = o;
}

__global__ __launch_bounds__(256) void fill_csr(
    const int* __restrict__ ei, const int* __restrict__ ekey,
    int* __restrict__ cursor, int* __restrict__ esrc)
{
  int e = blockIdx.x * 256 + threadIdx.x;
  if (e >= E_EDGES) return;
  int pos = atomicAdd(&cursor[ekey[e]], 1);
  esrc[pos] = ei[e];
}

// ---------------- gather S: one wave per (node,type) segment ----------------
__global__ __launch_bounds__(256) void gather_S(
    const ushort* __restrict__ m, const int* __restrict__ offs4,
    const int* __restrict__ esrc, ushort* __restrict__ S, int nSeg)
{
  const int wave = threadIdx.x >> 6, lane = threadIdx.x & 63;
  const int seg = blockIdx.x * 4 + wave;
  if (seg >= nSeg) return;
  const int beg = offs4[seg];
  const int end = offs4[seg + 1];
  const int ch = lane * 2;
  float ax = 0.f, ay = 0.f;
  int j = beg;
  for (; j + 3 < end; j += 4) {
    int s0 = esrc[j], s1 = esrc[j + 1], s2 = esrc[j + 2], s3 = esrc[j + 3];
    uint h0 = *(const uint*)(m + (size_t)s0 * 128 + ch);
    uint h1 = *(const uint*)(m + (size_t)s1 * 128 + ch);
    uint h2 = *(const uint*)(m + (size_t)s2 * 128 + ch);
    uint h3 = *(const uint*)(m + (size_t)s3 * 128 + ch);
    ax += bf2f((ushort)(h0 & 0xffff)) + bf2f((ushort)(h1 & 0xffff))
        + bf2f((ushort)(h2 & 0xffff)) + bf2f((ushort)(h3 & 0xffff));
    ay += bf2f((ushort)(h0 >> 16)) + bf2f((ushort)(h1 >> 16))
        + bf2f((ushort)(h2 >> 16)) + bf2f((ushort)(h3 >> 16));
  }
  for (; j < end; ++j) {
    uint h0 = *(const uint*)(m + (size_t)esrc[j] * 128 + ch);
    ax += bf2f((ushort)(h0 & 0xffff));
    ay += bf2f((ushort)(h0 >> 16));
  }
  // seg = node*4 + t  ->  S[node*512 + t*128 + ch]
  *(uint*)(S + (size_t)seg * 128 + ch) = (uint)f2bf(ax) | ((uint)f2bf(ay) << 16);
}

extern "C" void kernel_launch(void* const* d_in, const int* in_sizes, int n_in,
                              void* d_out, int out_size, void* d_ws, size_t ws_size,
                              hipStream_t stream) {
  const float* x     = (const float*)d_in[0];
  const int*   ei    = (const int*)d_in[1];
  const float* eattr = (const float*)d_in[2];
  const float* lin_w = (const float*)d_in[3];
  const float* lin_b = (const float*)d_in[4];
  const float* gnn_w = (const float*)d_in[5];
  const float* w_ih  = (const float*)d_in[6];
  const float* w_hh  = (const float*)d_in[7];
  const float* b_ih  = (const float*)d_in[8];
  const float* b_hh  = (const float*)d_in[9];
  const float* mu_w  = (const float*)d_in[10];
  const float* mu_b  = (const float*)d_in[11];
  const float* lv_w  = (const float*)d_in[12];
  const float* lv_b  = (const float*)d_in[13];

  char* ws = (char*)d_ws;
  size_t off = 0;
  ushort* x0b = (ushort*)(ws + off); off += (size_t)N_NODES * L * 2;        // 12.8MB
  ushort* ghb = (ushort*)(ws + off); off += (size_t)N_NODES * 3 * L * 2;    // 38.4MB
  ushort* m_b = (ushort*)(ws + off); off += (size_t)N_NODES * L * 2;        // 12.8MB
  ushort* S   = (ushort*)(ws + off); off += (size_t)N_NODES * 4 * L * 2;    // 51.2MB
  ushort* wsb = (ushort*)(ws + off); off += (size_t)WTOT * 2;
  ushort* wcomb = (ushort*)(ws + off); off += (size_t)STEPS * 384 * 512 * 2; // 1.18MB
  int* counts  = (int*)(ws + off); off += (NB4 + 1024) * 4;
  int* excl    = (int*)(ws + off); off += (NB4 + 1024) * 4;
  int* offs4   = (int*)(ws + off); off += (NB4 + 1024) * 4;
  int* cursor4 = (int*)(ws + off); off += (NB4 + 1024) * 4;
  int* bsum    = (int*)(ws + off); off += 256 * 4;
  int* boff    = (int*)(ws + off); off += 256 * 4;
  int* ekey    = (int*)(ws + off); off += (size_t)E_EDGES * 4;
  int* esrc    = (int*)(ws + off); off += (size_t)E_EDGES * 4;

  dim3 blk(256);
  const int GEMM_GRID = (N_NODES + 127) / 128;   // 391  (K=128 gemms)
  const int GRU_GRID  = (N_NODES + 63) / 64;     // 782  (64 rows/block)
  const int NSB = (NB4 + 1023) / 1024;           // 196

  convert_weights<<<(WTOT + 255) / 256, blk, 0, stream>>>(w_hh, mu_w, lv_w, wsb);
  make_wcomb<<<(STEPS * 384 * 512 + 255) / 256, blk, 0, stream>>>(w_ih, gnn_w, wcomb);

  // CSR keyed by (dst*4+type), constant across steps
  hipMemsetAsync(counts, 0, NB4 * sizeof(int), stream);
  hist_key<<<(E_EDGES + 255) / 256, blk, 0, stream>>>(ei, eattr, counts, ekey);
  scan_block<<<NSB, 1024, 0, stream>>>(counts, excl, bsum, NB4);
  scan_bsums<<<1, 256, 0, stream>>>(bsum, boff, NSB);
  scan_final<<<NSB, 1024, 0, stream>>>(excl, boff, offs4, cursor4, NB4);
  fill_csr<<<(E_EDGES + 255) / 256, blk, 0, stream>>>(ei, ekey, cursor4, esrc);

  // x0 = relu(x @ lin_w^T + lin_b) -> bf16
  dim3 g_x0((N_NODES + BN - 1) / BN, L / BO);
  matmul_x0<<<g_x0, blk, 0, stream>>>(x, lin_w, lin_b, x0b, N_NODES, IN_F, L);

  // gh = x0 @ w_hh^T + b_hh -> bf16
  gemm_mfma<384, 0><<<GEMM_GRID, blk, 0, stream>>>(
      x0b, wsb + WOFF_WHH, b_hh, nullptr, ghb, nullptr, nullptr, N_NODES);

  const ushort* mcur = x0b;
  for (int s = 0; s < STEPS; ++s) {
    gather_S<<<(NB4 + 3) / 4, blk, 0, stream>>>(mcur, offs4, esrc, S, NB4);
    gru_gemm<<<GRU_GRID, blk, 0, stream>>>(
        S, wcomb + (size_t)s * 384 * 512, b_ih, ghb, x0b, m_b, N_NODES);
    mcur = m_b;
  }

  float* mu = (float*)d_out;
  float* lv = (float*)d_out + (size_t)N_NODES * L;
  gemm_mfma<256, 4><<<GEMM_GRID, blk, 0, stream>>>(
      m_b, wsb + WOFF_HEADS, mu_b, mu, nullptr, lv_b, lv, N_NODES);
}

// Round 10
// 705.282 us; speedup vs baseline: 1.2913x; 1.2913x over previous
//
#include <hip/hip_runtime.h>
#include <hip/hip_bf16.h>
#include <cmath>

#define N_NODES 50000
#define IN_F 64
#define L 128
#define STEPS 3
#define T_TYPES 4
#define E_EDGES 800000
#define NB4 (N_NODES * 4)

typedef __attribute__((ext_vector_type(8))) __bf16 bf16x8_t;
typedef __attribute__((ext_vector_type(4))) float f32x4;

__device__ inline float bf2f(ushort u) {
  union { uint i; float f; } v; v.i = ((uint)u) << 16; return v.f;
}
__device__ inline ushort f2bf(float f) {
  union { float f; uint u; } v; v.f = f;
  uint u = v.u;
  u += 0x7fffu + ((u >> 16) & 1u);  // RNE
  return (ushort)(u >> 16);
}

// ---------------- fp32 tiled matmul for x0 (K=64), writes bf16 ----------------
#define BN 64
#define BO 64
#define BK 16
__global__ __launch_bounds__(256) void matmul_x0(
    const float* __restrict__ A, const float* __restrict__ W,
    const float* __restrict__ bias, ushort* __restrict__ Cb,
    int N, int K, int OUT)
{
  __shared__ float As[BN][BK + 1];
  __shared__ float Ws[BO][BK + 1];
  const int tid = threadIdx.x;
  const int n_base = blockIdx.x * BN;
  const int o_base = blockIdx.y * BO;
  const int tx = tid & 15, ty = tid >> 4;
  const int n0 = ty * 4, o0 = tx * 4;
  const int lr = tid >> 2, lc = (tid & 3) * 4;
  float acc[4][4] = {{0.f, 0.f, 0.f, 0.f}};
  for (int kc = 0; kc < K; kc += BK) {
    int gn = n_base + lr;
    float4 av = make_float4(0.f, 0.f, 0.f, 0.f);
    if (gn < N) av = *(const float4*)(A + (size_t)gn * K + kc + lc);
    As[lr][lc + 0] = av.x; As[lr][lc + 1] = av.y;
    As[lr][lc + 2] = av.z; As[lr][lc + 3] = av.w;
    float4 wv = *(const float4*)(W + (size_t)(o_base + lr) * K + kc + lc);
    Ws[lr][lc + 0] = wv.x; Ws[lr][lc + 1] = wv.y;
    Ws[lr][lc + 2] = wv.z; Ws[lr][lc + 3] = wv.w;
    __syncthreads();
#pragma unroll
    for (int kk = 0; kk < BK; ++kk) {
      float a[4], w[4];
#pragma unroll
      for (int i = 0; i < 4; ++i) a[i] = As[n0 + i][kk];
#pragma unroll
      for (int j = 0; j < 4; ++j) w[j] = Ws[o0 + j][kk];
#pragma unroll
      for (int i = 0; i < 4; ++i)
#pragma unroll
        for (int j = 0; j < 4; ++j) acc[i][j] += a[i] * w[j];
    }
    __syncthreads();
  }
#pragma unroll
  for (int i = 0; i < 4; ++i) {
    int gn = n_base + n0 + i;
    if (gn >= N) continue;
    int o = o_base + o0;
    float v0 = fmaxf(acc[i][0] + bias[o + 0], 0.f);
    float v1 = fmaxf(acc[i][1] + bias[o + 1], 0.f);
    float v2 = fmaxf(acc[i][2] + bias[o + 2], 0.f);
    float v3 = fmaxf(acc[i][3] + bias[o + 3], 0.f);
    uint2 pk;
    pk.x = (uint)f2bf(v0) | ((uint)f2bf(v1) << 16);
    pk.y = (uint)f2bf(v2) | ((uint)f2bf(v3) << 16);
    *(uint2*)(Cb + (size_t)gn * OUT + o) = pk;
  }
}

// ---------------- MFMA GEMM (K=128): KIND 0: bf16+bias (gh). KIND 4: heads mu/lv f32 ----------------
template<int OUT, int KIND>
__global__ __launch_bounds__(256) void gemm_mfma(
    const ushort* __restrict__ A, const ushort* __restrict__ W,
    const float* __restrict__ bias, float* __restrict__ Cf,
    ushort* __restrict__ Cb, const float* __restrict__ bias2,
    float* __restrict__ Cf2, int N)
{
  constexpr int K = 128;
  constexpr int NOT = OUT / 16;
  const int lane = threadIdx.x & 63;
  const int wave = threadIdx.x >> 6;
  const int r = lane & 15;
  const int kg = lane >> 4;
  const int row0 = (blockIdx.x * 8 + wave * 2) * 16;
  if (row0 >= N) return;

  int arow0 = row0 + r;          if (arow0 >= N) arow0 = N - 1;
  int arow1 = row0 + 16 + r;     if (arow1 >= N) arow1 = N - 1;
  const ushort* ap0 = A + (size_t)arow0 * K + kg * 8;
  const ushort* ap1 = A + (size_t)arow1 * K + kg * 8;
  const ushort* wp = W + (size_t)r * K + kg * 8;

  bf16x8_t af[2][4];
#pragma unroll
  for (int kt = 0; kt < 4; ++kt) {
    af[0][kt] = *(const bf16x8_t*)(ap0 + kt * 32);
    af[1][kt] = *(const bf16x8_t*)(ap1 + kt * 32);
  }
#pragma unroll
  for (int otp = 0; otp < NOT / 2; ++otp) {
    bf16x8_t w0[4], w1[4];
#pragma unroll
    for (int kt = 0; kt < 4; ++kt) {
      w0[kt] = *(const bf16x8_t*)(wp + (size_t)(2 * otp) * 16 * K + kt * 32);
      w1[kt] = *(const bf16x8_t*)(wp + (size_t)(2 * otp + 1) * 16 * K + kt * 32);
    }
    f32x4 acc[2][2] = {{{0.f,0.f,0.f,0.f},{0.f,0.f,0.f,0.f}},
                       {{0.f,0.f,0.f,0.f},{0.f,0.f,0.f,0.f}}};
#pragma unroll
    for (int kt = 0; kt < 4; ++kt) {
#pragma unroll
      for (int rt = 0; rt < 2; ++rt) {
        acc[rt][0] = __builtin_amdgcn_mfma_f32_16x16x32_bf16(af[rt][kt], w0[kt], acc[rt][0], 0, 0, 0);
        acc[rt][1] = __builtin_amdgcn_mfma_f32_16x16x32_bf16(af[rt][kt], w1[kt], acc[rt][1], 0, 0, 0);
      }
    }
#pragma unroll
    for (int rt = 0; rt < 2; ++rt) {
#pragma unroll
      for (int oi = 0; oi < 2; ++oi) {
        int o = (2 * otp + oi) * 16 + r;
#pragma unroll
        for (int reg = 0; reg < 4; ++reg) {
          int n = row0 + rt * 16 + kg * 4 + reg;
          if (n >= N) continue;
          float v = acc[rt][oi][reg];
          if constexpr (KIND == 0) {
            Cb[(size_t)n * OUT + o] = f2bf(v + bias[o]);
          } else {
            if (o < 128) Cf[(size_t)n * 128 + o] = v + bias[o];
            else Cf2[(size_t)n * 128 + (o - 128)] = v + bias2[o - 128];
          }
        }
      }
    }
  }
}

// ---------------- S-gemm: agg = S @ Wg^T  (K=512, OUT=128), high occupancy ----------------
// block = 16 rows x 128 out; wave owns 2 out-tiles; A-frags register-resident.
__global__ __launch_bounds__(256) void sgemm(
    const ushort* __restrict__ S, const ushort* __restrict__ Wg,
    ushort* __restrict__ aggb, int N)
{
  const int lane = threadIdx.x & 63;
  const int wave = threadIdx.x >> 6;
  const int r = lane & 15;
  const int kg = lane >> 4;
  const int row0 = blockIdx.x * 16;
  int arow = row0 + r; if (arow >= N) arow = N - 1;
  const ushort* ap = S + (size_t)arow * 512 + kg * 8;

  bf16x8_t af[16];
#pragma unroll
  for (int kt = 0; kt < 16; ++kt) af[kt] = *(const bf16x8_t*)(ap + kt * 32);

  const ushort* wp = Wg + ((size_t)(wave * 32 + r)) * 512 + kg * 8;
  f32x4 acc0 = {0.f,0.f,0.f,0.f}, acc1 = {0.f,0.f,0.f,0.f};
#pragma unroll
  for (int kt = 0; kt < 16; ++kt) {
    bf16x8_t w0 = *(const bf16x8_t*)(wp + kt * 32);
    bf16x8_t w1 = *(const bf16x8_t*)(wp + (size_t)16 * 512 + kt * 32);
    acc0 = __builtin_amdgcn_mfma_f32_16x16x32_bf16(af[kt], w0, acc0, 0, 0, 0);
    acc1 = __builtin_amdgcn_mfma_f32_16x16x32_bf16(af[kt], w1, acc1, 0, 0, 0);
  }
#pragma unroll
  for (int reg = 0; reg < 4; ++reg) {
    int n = row0 + kg * 4 + reg;
    if (n >= N) continue;
    aggb[(size_t)n * 128 + wave * 32 + r]      = f2bf(acc0[reg]);
    aggb[(size_t)n * 128 + wave * 32 + 16 + r] = f2bf(acc1[reg]);
  }
}

// ---------------- GRU gemm: gi = agg @ w_ih^T (K=128) + gate epilogue, high occupancy ----------------
// block = 16 rows x 384 out; wave owns jg = {wave, wave+4} (gate-triples).
__global__ __launch_bounds__(256) void gru_gemm(
    const ushort* __restrict__ A, const ushort* __restrict__ Wih,
    const float* __restrict__ bias, const ushort* __restrict__ ghb,
    const ushort* __restrict__ x0b, ushort* __restrict__ m_out, int N)
{
  const int lane = threadIdx.x & 63;
  const int wave = threadIdx.x >> 6;
  const int r = lane & 15;
  const int kg = lane >> 4;
  const int row0 = blockIdx.x * 16;
  int arow = row0 + r; if (arow >= N) arow = N - 1;
  const ushort* ap = A + (size_t)arow * 128 + kg * 8;

  bf16x8_t af[4];
#pragma unroll
  for (int kt = 0; kt < 4; ++kt) af[kt] = *(const bf16x8_t*)(ap + kt * 32);

#pragma unroll
  for (int jl = 0; jl < 2; ++jl) {
    const int jg = wave + jl * 4;
    const ushort* wr = Wih + ((size_t)(0 * 128 + jg * 16 + r)) * 128 + kg * 8;
    const ushort* wz = Wih + ((size_t)(1 * 128 + jg * 16 + r)) * 128 + kg * 8;
    const ushort* wn = Wih + ((size_t)(2 * 128 + jg * 16 + r)) * 128 + kg * 8;
    f32x4 ar = {0.f,0.f,0.f,0.f}, az = {0.f,0.f,0.f,0.f}, an = {0.f,0.f,0.f,0.f};
#pragma unroll
    for (int kt = 0; kt < 4; ++kt) {
      bf16x8_t vr = *(const bf16x8_t*)(wr + kt * 32);
      bf16x8_t vz = *(const bf16x8_t*)(wz + kt * 32);
      bf16x8_t vn = *(const bf16x8_t*)(wn + kt * 32);
      ar = __builtin_amdgcn_mfma_f32_16x16x32_bf16(af[kt], vr, ar, 0, 0, 0);
      az = __builtin_amdgcn_mfma_f32_16x16x32_bf16(af[kt], vz, az, 0, 0, 0);
      an = __builtin_amdgcn_mfma_f32_16x16x32_bf16(af[kt], vn, an, 0, 0, 0);
    }
    const int j = jg * 16 + r;
    const float br = bias[j], bz = bias[128 + j], bn = bias[256 + j];
#pragma unroll
    for (int reg = 0; reg < 4; ++reg) {
      int n = row0 + kg * 4 + reg;
      if (n >= N) continue;
      const ushort* ghp = ghb + (size_t)n * 384;
      float gir = ar[reg] + br + bf2f(ghp[j]);
      float giz = az[reg] + bz + bf2f(ghp[128 + j]);
      float ghn = bf2f(ghp[256 + j]);
      float rr = 1.f / (1.f + expf(-gir));
      float zz = 1.f / (1.f + expf(-giz));
      float nn = tanhf(an[reg] + bn + rr * ghn);
      float x0v = bf2f(x0b[(size_t)n * 128 + j]);
      float h = (1.f - zz) * nn + zz * x0v;
      m_out[(size_t)n * 128 + j] = f2bf(fmaxf(h, 0.f));
    }
  }
}

// ---------------- weight conversion f32 -> bf16 (packed segments) ----------------
// Wg[s][c][t*128+j] = 2 * gnn_w[s][t][c][j]
#define WOFF_WHH 0
#define WOFF_WIH 49152
#define WOFF_WG 98304
#define WOFF_HEADS 294912
#define WTOT 327680

__global__ __launch_bounds__(256) void convert_weights(
    const float* __restrict__ w_hh, const float* __restrict__ w_ih,
    const float* __restrict__ gnn_w, const float* __restrict__ mu_w,
    const float* __restrict__ lv_w, ushort* __restrict__ wsb)
{
  int i = blockIdx.x * 256 + threadIdx.x;
  if (i >= WTOT) return;
  float v;
  if (i < WOFF_WIH) v = w_hh[i];
  else if (i < WOFF_WG) v = w_ih[i - WOFF_WIH];
  else if (i < WOFF_HEADS) {
    int k = i - WOFF_WG;
    int s = k >> 16;
    int rr = k & 65535;
    int c = rr >> 9;
    int col = rr & 511;
    int t = col >> 7;
    int j = col & 127;
    v = 2.f * gnn_w[(((size_t)s * 4 + t) * 128 + c) * 128 + j];
  } else {
    int k = i - WOFF_HEADS;
    v = (k < 16384) ? mu_w[k] : lv_w[k - 16384];
  }
  wsb[i] = f2bf(v);
}

// ---------------- CSR build keyed by (dst*4 + type) ----------------
__global__ __launch_bounds__(256) void hist_key(
    const int* __restrict__ ei, const float* __restrict__ ea,
    int* __restrict__ counts, int* __restrict__ ekey)
{
  int e = blockIdx.x * 256 + threadIdx.x;
  if (e >= E_EDGES) return;
  const float* a = ea + (size_t)e * T_TYPES;
  float bv = a[0]; int bi = 0;
#pragma unroll
  for (int t = 1; t < T_TYPES; ++t) {
    float v = a[t];
    if (v > bv) { bv = v; bi = t; }
  }
  int key = ei[E_EDGES + e] * 4 + bi;
  ekey[e] = key;
  atomicAdd(&counts[key], 1);
}

__global__ __launch_bounds__(1024) void scan_block(
    const int* __restrict__ counts, int* __restrict__ excl,
    int* __restrict__ bsum, int n)
{
  __shared__ int ls[1024];
  const int tid = threadIdx.x;
  const int i = blockIdx.x * 1024 + tid;
  int v = (i < n) ? counts[i] : 0;
  ls[tid] = v;
  __syncthreads();
  for (int off = 1; off < 1024; off <<= 1) {
    int t = (tid >= off) ? ls[tid - off] : 0;
    __syncthreads();
    ls[tid] += t;
    __syncthreads();
  }
  if (i < n) excl[i] = ls[tid] - v;
  if (tid == 1023) bsum[blockIdx.x] = ls[1023];
}

__global__ __launch_bounds__(256) void scan_bsums(
    const int* __restrict__ bsum, int* __restrict__ boff, int nb)
{
  __shared__ int ls[256];
  const int tid = threadIdx.x;
  int v = (tid < nb) ? bsum[tid] : 0;
  ls[tid] = v;
  __syncthreads();
  for (int off = 1; off < 256; off <<= 1) {
    int t = (tid >= off) ? ls[tid - off] : 0;
    __syncthreads();
    ls[tid] += t;
    __syncthreads();
  }
  if (tid < nb) boff[tid] = ls[tid] - v;
}

__global__ __launch_bounds__(1024) void scan_final(
    const int* __restrict__ excl, const int* __restrict__ boff,
    int* __restrict__ offsets, int* __restrict__ cursor, int n)
{
  int i = blockIdx.x * 1024 + threadIdx.x;
  if (i == 0) { offsets[n] = E_EDGES; }
  if (i >= n) return;
  int o = excl[i] + boff[blockIdx.x];
  offsets[i] = o;
  cursor[i] = o;
}

__global__ __launch_bounds__(256) void fill_csr(
    const int* __restrict__ ei, const int* __restrict__ ekey,
    int* __restrict__ cursor, int* __restrict__ esrc)
{
  int e = blockIdx.x * 256 + threadIdx.x;
  if (e >= E_EDGES) return;
  int pos = atomicAdd(&cursor[ekey[e]], 1);
  esrc[pos] = ei[e];
}

// ---------------- gather S: one wave per node; esrc preload + shfl broadcast ----------------
__global__ __launch_bounds__(256) void gather_S(
    const ushort* __restrict__ m, const int* __restrict__ offs4,
    const int* __restrict__ esrc, ushort* __restrict__ S, int nNodes)
{
  const int wave = threadIdx.x >> 6, lane = threadIdx.x & 63;
  const int node = blockIdx.x * 4 + wave;
  if (node >= nNodes) return;
  const int b0 = offs4[node * 4 + 0];
  const int b1 = offs4[node * 4 + 1];
  const int b2 = offs4[node * 4 + 2];
  const int b3 = offs4[node * 4 + 3];
  const int b4 = offs4[node * 4 + 4];
  // one coalesced load covers up to 64 edges of this node
  int idx = b0 + lane;
  int pre = (idx < b4) ? esrc[idx] : 0;
  const int ch = lane * 2;
  uint* sp = (uint*)(S + (size_t)node * 512 + ch);

  float ax0, ay0, ax1, ay1;
#define GSEG(BT, ET, SLOT)                                                    \
  ax0 = 0.f; ay0 = 0.f; ax1 = 0.f; ay1 = 0.f;                                 \
  {                                                                           \
    int j = BT;                                                               \
    for (; j + 1 < ET; j += 2) {                                              \
      int r0 = j - b0, r1 = r0 + 1;                                           \
      int s0 = (r0 < 64) ? __shfl(pre, r0) : esrc[j];                         \
      int s1 = (r1 < 64) ? __shfl(pre, r1) : esrc[j + 1];                     \
      uint h0 = *(const uint*)(m + (size_t)s0 * 128 + ch);                    \
      uint h1 = *(const uint*)(m + (size_t)s1 * 128 + ch);                    \
      ax0 += bf2f((ushort)(h0 & 0xffff)); ay0 += bf2f((ushort)(h0 >> 16));    \
      ax1 += bf2f((ushort)(h1 & 0xffff)); ay1 += bf2f((ushort)(h1 >> 16));    \
    }                                                                         \
    if (j < ET) {                                                             \
      int r0 = j - b0;                                                        \
      int s0 = (r0 < 64) ? __shfl(pre, r0) : esrc[j];                         \
      uint h0 = *(const uint*)(m + (size_t)s0 * 128 + ch);                    \
      ax0 += bf2f((ushort)(h0 & 0xffff)); ay0 += bf2f((ushort)(h0 >> 16));    \
    }                                                                         \
  }                                                                           \
  sp[SLOT * 64] = (uint)f2bf(ax0 + ax1) | ((uint)f2bf(ay0 + ay1) << 16);

  GSEG(b0, b1, 0)
  GSEG(b1, b2, 1)
  GSEG(b2, b3, 2)
  GSEG(b3, b4, 3)
#undef GSEG
}

extern "C" void kernel_launch(void* const* d_in, const int* in_sizes, int n_in,
                              void* d_out, int out_size, void* d_ws, size_t ws_size,
                              hipStream_t stream) {
  const float* x     = (const float*)d_in[0];
  const int*   ei    = (const int*)d_in[1];
  const float* eattr = (const float*)d_in[2];
  const float* lin_w = (const float*)d_in[3];
  const float* lin_b = (const float*)d_in[4];
  const float* gnn_w = (const float*)d_in[5];
  const float* w_ih  = (const float*)d_in[6];
  const float* w_hh  = (const float*)d_in[7];
  const float* b_ih  = (const float*)d_in[8];
  const float* b_hh  = (const float*)d_in[9];
  const float* mu_w  = (const float*)d_in[10];
  const float* mu_b  = (const float*)d_in[11];
  const float* lv_w  = (const float*)d_in[12];
  const float* lv_b  = (const float*)d_in[13];

  char* ws = (char*)d_ws;
  size_t off = 0;
  ushort* x0b = (ushort*)(ws + off); off += (size_t)N_NODES * L * 2;        // 12.8MB
  ushort* ghb = (ushort*)(ws + off); off += (size_t)N_NODES * 3 * L * 2;    // 38.4MB
  ushort* m_b = (ushort*)(ws + off); off += (size_t)N_NODES * L * 2;        // 12.8MB
  ushort* aggb= (ushort*)(ws + off); off += (size_t)N_NODES * L * 2;        // 12.8MB
  ushort* S   = (ushort*)(ws + off); off += (size_t)N_NODES * 4 * L * 2;    // 51.2MB
  ushort* wsb = (ushort*)(ws + off); off += (size_t)WTOT * 2;               // 0.66MB
  int* counts  = (int*)(ws + off); off += (NB4 + 1024) * 4;
  int* excl    = (int*)(ws + off); off += (NB4 + 1024) * 4;
  int* offs4   = (int*)(ws + off); off += (NB4 + 1024) * 4;
  int* cursor4 = (int*)(ws + off); off += (NB4 + 1024) * 4;
  int* bsum    = (int*)(ws + off); off += 256 * 4;
  int* boff    = (int*)(ws + off); off += 256 * 4;
  int* ekey    = (int*)(ws + off); off += (size_t)E_EDGES * 4;
  int* esrc    = (int*)(ws + off); off += (size_t)E_EDGES * 4;

  dim3 blk(256);
  const int GEMM_GRID = (N_NODES + 127) / 128;   // 391 (gh, heads)
  const int TILE_GRID = (N_NODES + 15) / 16;     // 3125 (sgemm, gru)
  const int NSB = (NB4 + 1023) / 1024;           // 196

  convert_weights<<<(WTOT + 255) / 256, blk, 0, stream>>>(
      w_hh, w_ih, gnn_w, mu_w, lv_w, wsb);

  // CSR keyed by (dst*4+type), constant across steps
  hipMemsetAsync(counts, 0, NB4 * sizeof(int), stream);
  hist_key<<<(E_EDGES + 255) / 256, blk, 0, stream>>>(ei, eattr, counts, ekey);
  scan_block<<<NSB, 1024, 0, stream>>>(counts, excl, bsum, NB4);
  scan_bsums<<<1, 256, 0, stream>>>(bsum, boff, NSB);
  scan_final<<<NSB, 1024, 0, stream>>>(excl, boff, offs4, cursor4, NB4);
  fill_csr<<<(E_EDGES + 255) / 256, blk, 0, stream>>>(ei, ekey, cursor4, esrc);

  // x0 = relu(x @ lin_w^T + lin_b) -> bf16
  dim3 g_x0((N_NODES + BN - 1) / BN, L / BO);
  matmul_x0<<<g_x0, blk, 0, stream>>>(x, lin_w, lin_b, x0b, N_NODES, IN_F, L);

  // gh = x0 @ w_hh^T + b_hh -> bf16
  gemm_mfma<384, 0><<<GEMM_GRID, blk, 0, stream>>>(
      x0b, wsb + WOFF_WHH, b_hh, nullptr, ghb, nullptr, nullptr, N_NODES);

  const ushort* mcur = x0b;
  for (int s = 0; s < STEPS; ++s) {
    gather_S<<<(N_NODES + 3) / 4, blk, 0, stream>>>(mcur, offs4, esrc, S, N_NODES);
    sgemm<<<TILE_GRID, blk, 0, stream>>>(
        S, wsb + WOFF_WG + (size_t)s * 65536, aggb, N_NODES);
    gru_gemm<<<TILE_GRID, blk, 0, stream>>>(
        aggb, wsb + WOFF_WIH, b_ih, ghb, x0b, m_b, N_NODES);
    mcur = m_b;
  }

  float* mu = (float*)d_out;
  float* lv = (float*)d_out + (size_t)N_NODES * L;
  gemm_mfma<256, 4><<<GEMM_GRID, blk, 0, stream>>>(
      m_b, wsb + WOFF_HEADS, mu_b, mu, nullptr, lv_b, lv, N_NODES);
}

// Round 11
// 587.904 us; speedup vs baseline: 1.5491x; 1.1997x over previous
//
#include <hip/hip_runtime.h>
#include <hip/hip_bf16.h>
#include <cmath>

#define N_NODES 50000
#define IN_F 64
#define L 128
#define STEPS 3
#define T_TYPES 4
#define E_EDGES 800000
#define NB4 (N_NODES * 4)

typedef __attribute__((ext_vector_type(8))) __bf16 bf16x8_t;
typedef __attribute__((ext_vector_type(4))) float f32x4;

__device__ inline float bf2f(ushort u) {
  union { uint i; float f; } v; v.i = ((uint)u) << 16; return v.f;
}
__device__ inline ushort f2bf(float f) {
  union { float f; uint u; } v; v.f = f;
  uint u = v.u;
  u += 0x7fffu + ((u >> 16) & 1u);  // RNE
  return (ushort)(u >> 16);
}

// ---------------- fp32 tiled matmul for x0 (K=64), writes bf16 ----------------
#define BN 64
#define BO 64
#define BK 16
__global__ __launch_bounds__(256) void matmul_x0(
    const float* __restrict__ A, const float* __restrict__ W,
    const float* __restrict__ bias, ushort* __restrict__ Cb,
    int N, int K, int OUT)
{
  __shared__ float As[BN][BK + 1];
  __shared__ float Ws[BO][BK + 1];
  const int tid = threadIdx.x;
  const int n_base = blockIdx.x * BN;
  const int o_base = blockIdx.y * BO;
  const int tx = tid & 15, ty = tid >> 4;
  const int n0 = ty * 4, o0 = tx * 4;
  const int lr = tid >> 2, lc = (tid & 3) * 4;
  float acc[4][4] = {{0.f, 0.f, 0.f, 0.f}};
  for (int kc = 0; kc < K; kc += BK) {
    int gn = n_base + lr;
    float4 av = make_float4(0.f, 0.f, 0.f, 0.f);
    if (gn < N) av = *(const float4*)(A + (size_t)gn * K + kc + lc);
    As[lr][lc + 0] = av.x; As[lr][lc + 1] = av.y;
    As[lr][lc + 2] = av.z; As[lr][lc + 3] = av.w;
    float4 wv = *(const float4*)(W + (size_t)(o_base + lr) * K + kc + lc);
    Ws[lr][lc + 0] = wv.x; Ws[lr][lc + 1] = wv.y;
    Ws[lr][lc + 2] = wv.z; Ws[lr][lc + 3] = wv.w;
    __syncthreads();
#pragma unroll
    for (int kk = 0; kk < BK; ++kk) {
      float a[4], w[4];
#pragma unroll
      for (int i = 0; i < 4; ++i) a[i] = As[n0 + i][kk];
#pragma unroll
      for (int j = 0; j < 4; ++j) w[j] = Ws[o0 + j][kk];
#pragma unroll
      for (int i = 0; i < 4; ++i)
#pragma unroll
        for (int j = 0; j < 4; ++j) acc[i][j] += a[i] * w[j];
    }
    __syncthreads();
  }
#pragma unroll
  for (int i = 0; i < 4; ++i) {
    int gn = n_base + n0 + i;
    if (gn >= N) continue;
    int o = o_base + o0;
    float v0 = fmaxf(acc[i][0] + bias[o + 0], 0.f);
    float v1 = fmaxf(acc[i][1] + bias[o + 1], 0.f);
    float v2 = fmaxf(acc[i][2] + bias[o + 2], 0.f);
    float v3 = fmaxf(acc[i][3] + bias[o + 3], 0.f);
    uint2 pk;
    pk.x = (uint)f2bf(v0) | ((uint)f2bf(v1) << 16);
    pk.y = (uint)f2bf(v2) | ((uint)f2bf(v3) << 16);
    *(uint2*)(Cb + (size_t)gn * OUT + o) = pk;
  }
}

// ---------------- MFMA GEMM (K=128): KIND 0: bf16+bias (gh). KIND 4: heads mu/lv f32 ----------------
template<int OUT, int KIND>
__global__ __launch_bounds__(256) void gemm_mfma(
    const ushort* __restrict__ A, const ushort* __restrict__ W,
    const float* __restrict__ bias, float* __restrict__ Cf,
    ushort* __restrict__ Cb, const float* __restrict__ bias2,
    float* __restrict__ Cf2, int N)
{
  constexpr int K = 128;
  constexpr int NOT = OUT / 16;
  const int lane = threadIdx.x & 63;
  const int wave = threadIdx.x >> 6;
  const int r = lane & 15;
  const int kg = lane >> 4;
  const int row0 = (blockIdx.x * 8 + wave * 2) * 16;
  if (row0 >= N) return;

  int arow0 = row0 + r;          if (arow0 >= N) arow0 = N - 1;
  int arow1 = row0 + 16 + r;     if (arow1 >= N) arow1 = N - 1;
  const ushort* ap0 = A + (size_t)arow0 * K + kg * 8;
  const ushort* ap1 = A + (size_t)arow1 * K + kg * 8;
  const ushort* wp = W + (size_t)r * K + kg * 8;

  bf16x8_t af[2][4];
#pragma unroll
  for (int kt = 0; kt < 4; ++kt) {
    af[0][kt] = *(const bf16x8_t*)(ap0 + kt * 32);
    af[1][kt] = *(const bf16x8_t*)(ap1 + kt * 32);
  }
#pragma unroll
  for (int otp = 0; otp < NOT / 2; ++otp) {
    bf16x8_t w0[4], w1[4];
#pragma unroll
    for (int kt = 0; kt < 4; ++kt) {
      w0[kt] = *(const bf16x8_t*)(wp + (size_t)(2 * otp) * 16 * K + kt * 32);
      w1[kt] = *(const bf16x8_t*)(wp + (size_t)(2 * otp + 1) * 16 * K + kt * 32);
    }
    f32x4 acc[2][2] = {{{0.f,0.f,0.f,0.f},{0.f,0.f,0.f,0.f}},
                       {{0.f,0.f,0.f,0.f},{0.f,0.f,0.f,0.f}}};
#pragma unroll
    for (int kt = 0; kt < 4; ++kt) {
#pragma unroll
      for (int rt = 0; rt < 2; ++rt) {
        acc[rt][0] = __builtin_amdgcn_mfma_f32_16x16x32_bf16(af[rt][kt], w0[kt], acc[rt][0], 0, 0, 0);
        acc[rt][1] = __builtin_amdgcn_mfma_f32_16x16x32_bf16(af[rt][kt], w1[kt], acc[rt][1], 0, 0, 0);
      }
    }
#pragma unroll
    for (int rt = 0; rt < 2; ++rt) {
#pragma unroll
      for (int oi = 0; oi < 2; ++oi) {
        int o = (2 * otp + oi) * 16 + r;
#pragma unroll
        for (int reg = 0; reg < 4; ++reg) {
          int n = row0 + rt * 16 + kg * 4 + reg;
          if (n >= N) continue;
          float v = acc[rt][oi][reg];
          if constexpr (KIND == 0) {
            Cb[(size_t)n * OUT + o] = f2bf(v + bias[o]);
          } else {
            if (o < 128) Cf[(size_t)n * 128 + o] = v + bias[o];
            else Cf2[(size_t)n * 128 + (o - 128)] = v + bias2[o - 128];
          }
        }
      }
    }
  }
}

// ---------------- fused step: gather->LDS, sgemm->LDS, GRU->m_out ----------------
// block = 16 nodes, 4 waves. s_lds[16][512] and a_lds[16][128] XOR-swizzled:
// byte ^= ((row&7)<<4) so column-slice b128 reads hit 8 distinct 16B slots (2-way, free).
__global__ __launch_bounds__(256) void step_fused(
    const ushort* __restrict__ m, const int* __restrict__ offs4,
    const int* __restrict__ esrc, const ushort* __restrict__ Wg,
    const ushort* __restrict__ Wih, const float* __restrict__ bias,
    const ushort* __restrict__ ghb, const ushort* __restrict__ x0b,
    ushort* __restrict__ m_out, int N)
{
  __shared__ ushort s_lds[16 * 512];   // 16KB
  __shared__ ushort a_lds[16 * 128];   // 4KB
  const int tid = threadIdx.x;
  const int lane = tid & 63;
  const int wave = tid >> 6;
  const int node0 = blockIdx.x * 16;

  // ---- phase 1: gather; wave handles 4 nodes ----
  {
    const int ch = lane * 2;
#pragma unroll
    for (int i = 0; i < 4; ++i) {
      const int row = wave * 4 + i;
      const int node = node0 + row;
      const int b0 = offs4[node * 4 + 0];
      const int b1 = offs4[node * 4 + 1];
      const int b2 = offs4[node * 4 + 2];
      const int b3 = offs4[node * 4 + 3];
      const int b4 = offs4[node * 4 + 4];
      int idx = b0 + lane;
      int pre = (idx < b4) ? esrc[idx] : 0;
      char* srow = (char*)s_lds + row * 1024;
      const int swz = (row & 7) << 4;
      float ax0, ay0, ax1, ay1;
#define GSEG(BT, ET, SLOT)                                                    \
      ax0 = 0.f; ay0 = 0.f; ax1 = 0.f; ay1 = 0.f;                             \
      {                                                                       \
        int j = BT;                                                           \
        for (; j + 1 < ET; j += 2) {                                          \
          int r0 = j - b0, r1 = r0 + 1;                                       \
          int s0 = (r0 < 64) ? __shfl(pre, r0) : esrc[j];                     \
          int s1 = (r1 < 64) ? __shfl(pre, r1) : esrc[j + 1];                 \
          uint h0 = *(const uint*)(m + (size_t)s0 * 128 + ch);                \
          uint h1 = *(const uint*)(m + (size_t)s1 * 128 + ch);                \
          ax0 += bf2f((ushort)(h0 & 0xffff)); ay0 += bf2f((ushort)(h0 >> 16));\
          ax1 += bf2f((ushort)(h1 & 0xffff)); ay1 += bf2f((ushort)(h1 >> 16));\
        }                                                                     \
        if (j < ET) {                                                         \
          int r0 = j - b0;                                                    \
          int s0 = (r0 < 64) ? __shfl(pre, r0) : esrc[j];                     \
          uint h0 = *(const uint*)(m + (size_t)s0 * 128 + ch);                \
          ax0 += bf2f((ushort)(h0 & 0xffff)); ay0 += bf2f((ushort)(h0 >> 16));\
        }                                                                     \
      }                                                                       \
      *(uint*)(srow + ((SLOT * 256 + lane * 4) ^ swz)) =                      \
          (uint)f2bf(ax0 + ax1) | ((uint)f2bf(ay0 + ay1) << 16);

      GSEG(b0, b1, 0)
      GSEG(b1, b2, 1)
      GSEG(b2, b3, 2)
      GSEG(b3, b4, 3)
#undef GSEG
    }
  }
  __syncthreads();

  const int r = lane & 15;
  const int kg = lane >> 4;
  const int rswz = (r & 7) << 4;

  // ---- phase 2: agg = S @ Wg^T (K=512); wave owns out cols [wave*32, wave*32+32) ----
  {
    const ushort* wp = Wg + (size_t)(wave * 32 + r) * 512 + kg * 8;
    f32x4 acc0 = {0.f,0.f,0.f,0.f}, acc1 = {0.f,0.f,0.f,0.f};
#pragma unroll
    for (int kt = 0; kt < 16; ++kt) {
      bf16x8_t w0 = *(const bf16x8_t*)(wp + kt * 32);
      bf16x8_t w1 = *(const bf16x8_t*)(wp + (size_t)16 * 512 + kt * 32);
      bf16x8_t af = *(const bf16x8_t*)((const char*)s_lds +
                      ((r * 1024 + kg * 16 + kt * 64) ^ rswz));
      acc0 = __builtin_amdgcn_mfma_f32_16x16x32_bf16(af, w0, acc0, 0, 0, 0);
      acc1 = __builtin_amdgcn_mfma_f32_16x16x32_bf16(af, w1, acc1, 0, 0, 0);
    }
#pragma unroll
    for (int reg = 0; reg < 4; ++reg) {
      int row = kg * 4 + reg;
      int sw = (row & 7) << 4;
      *(ushort*)((char*)a_lds + ((row * 256 + (wave * 32 + r) * 2) ^ sw)) = f2bf(acc0[reg]);
      *(ushort*)((char*)a_lds + ((row * 256 + (wave * 32 + 16 + r) * 2) ^ sw)) = f2bf(acc1[reg]);
    }
  }
  __syncthreads();

  // ---- phase 3: gi = agg @ w_ih^T (K=128) + GRU epilogue; wave owns jg={wave,wave+4} ----
  bf16x8_t af2[4];
#pragma unroll
  for (int kt = 0; kt < 4; ++kt)
    af2[kt] = *(const bf16x8_t*)((const char*)a_lds +
                ((r * 256 + kg * 16 + kt * 64) ^ rswz));

#pragma unroll
  for (int jl = 0; jl < 2; ++jl) {
    const int jg = wave + jl * 4;
    const ushort* wr = Wih + ((size_t)(0 * 128 + jg * 16 + r)) * 128 + kg * 8;
    const ushort* wz = Wih + ((size_t)(1 * 128 + jg * 16 + r)) * 128 + kg * 8;
    const ushort* wn = Wih + ((size_t)(2 * 128 + jg * 16 + r)) * 128 + kg * 8;
    f32x4 ar = {0.f,0.f,0.f,0.f}, az = {0.f,0.f,0.f,0.f}, an = {0.f,0.f,0.f,0.f};
#pragma unroll
    for (int kt = 0; kt < 4; ++kt) {
      bf16x8_t vr = *(const bf16x8_t*)(wr + kt * 32);
      bf16x8_t vz = *(const bf16x8_t*)(wz + kt * 32);
      bf16x8_t vn = *(const bf16x8_t*)(wn + kt * 32);
      ar = __builtin_amdgcn_mfma_f32_16x16x32_bf16(af2[kt], vr, ar, 0, 0, 0);
      az = __builtin_amdgcn_mfma_f32_16x16x32_bf16(af2[kt], vz, az, 0, 0, 0);
      an = __builtin_amdgcn_mfma_f32_16x16x32_bf16(af2[kt], vn, an, 0, 0, 0);
    }
    const int j = jg * 16 + r;
    const float br = bias[j], bz = bias[128 + j], bn = bias[256 + j];
#pragma unroll
    for (int reg = 0; reg < 4; ++reg) {
      int n = node0 + kg * 4 + reg;
      if (n >= N) continue;
      const ushort* ghp = ghb + (size_t)n * 384;
      float gir = ar[reg] + br + bf2f(ghp[j]);
      float giz = az[reg] + bz + bf2f(ghp[128 + j]);
      float ghn = bf2f(ghp[256 + j]);
      float rr = 1.f / (1.f + expf(-gir));
      float zz = 1.f / (1.f + expf(-giz));
      float nn = tanhf(an[reg] + bn + rr * ghn);
      float x0v = bf2f(x0b[(size_t)n * 128 + j]);
      float h = (1.f - zz) * nn + zz * x0v;
      m_out[(size_t)n * 128 + j] = f2bf(fmaxf(h, 0.f));
    }
  }
}

// ---------------- weight conversion f32 -> bf16 (packed segments) ----------------
// Wg[s][c][t*128+j] = 2 * gnn_w[s][t][c][j]
#define WOFF_WHH 0
#define WOFF_WIH 49152
#define WOFF_WG 98304
#define WOFF_HEADS 294912
#define WTOT 327680

__global__ __launch_bounds__(256) void convert_weights(
    const float* __restrict__ w_hh, const float* __restrict__ w_ih,
    const float* __restrict__ gnn_w, const float* __restrict__ mu_w,
    const float* __restrict__ lv_w, ushort* __restrict__ wsb)
{
  int i = blockIdx.x * 256 + threadIdx.x;
  if (i >= WTOT) return;
  float v;
  if (i < WOFF_WIH) v = w_hh[i];
  else if (i < WOFF_WG) v = w_ih[i - WOFF_WIH];
  else if (i < WOFF_HEADS) {
    int k = i - WOFF_WG;
    int s = k >> 16;
    int rr = k & 65535;
    int c = rr >> 9;
    int col = rr & 511;
    int t = col >> 7;
    int j = col & 127;
    v = 2.f * gnn_w[(((size_t)s * 4 + t) * 128 + c) * 128 + j];
  } else {
    int k = i - WOFF_HEADS;
    v = (k < 16384) ? mu_w[k] : lv_w[k - 16384];
  }
  wsb[i] = f2bf(v);
}

// ---------------- CSR build keyed by (dst*4 + type) ----------------
__global__ __launch_bounds__(256) void hist_key(
    const int* __restrict__ ei, const float* __restrict__ ea,
    int* __restrict__ counts, int* __restrict__ ekey)
{
  int e = blockIdx.x * 256 + threadIdx.x;
  if (e >= E_EDGES) return;
  const float* a = ea + (size_t)e * T_TYPES;
  float bv = a[0]; int bi = 0;
#pragma unroll
  for (int t = 1; t < T_TYPES; ++t) {
    float v = a[t];
    if (v > bv) { bv = v; bi = t; }
  }
  int key = ei[E_EDGES + e] * 4 + bi;
  ekey[e] = key;
  atomicAdd(&counts[key], 1);
}

__global__ __launch_bounds__(1024) void scan_block(
    const int* __restrict__ counts, int* __restrict__ excl,
    int* __restrict__ bsum, int n)
{
  __shared__ int ls[1024];
  const int tid = threadIdx.x;
  const int i = blockIdx.x * 1024 + tid;
  int v = (i < n) ? counts[i] : 0;
  ls[tid] = v;
  __syncthreads();
  for (int off = 1; off < 1024; off <<= 1) {
    int t = (tid >= off) ? ls[tid - off] : 0;
    __syncthreads();
    ls[tid] += t;
    __syncthreads();
  }
  if (i < n) excl[i] = ls[tid] - v;
  if (tid == 1023) bsum[blockIdx.x] = ls[1023];
}

__global__ __launch_bounds__(256) void scan_bsums(
    const int* __restrict__ bsum, int* __restrict__ boff, int nb)
{
  __shared__ int ls[256];
  const int tid = threadIdx.x;
  int v = (tid < nb) ? bsum[tid] : 0;
  ls[tid] = v;
  __syncthreads();
  for (int off = 1; off < 256; off <<= 1) {
    int t = (tid >= off) ? ls[tid - off] : 0;
    __syncthreads();
    ls[tid] += t;
    __syncthreads();
  }
  if (tid < nb) boff[tid] = ls[tid] - v;
}

__global__ __launch_bounds__(1024) void scan_final(
    const int* __restrict__ excl, const int* __restrict__ boff,
    int* __restrict__ offsets, int* __restrict__ cursor, int n)
{
  int i = blockIdx.x * 1024 + threadIdx.x;
  if (i == 0) { offsets[n] = E_EDGES; }
  if (i >= n) return;
  int o = excl[i] + boff[blockIdx.x];
  offsets[i] = o;
  cursor[i] = o;
}

__global__ __launch_bounds__(256) void fill_csr(
    const int* __restrict__ ei, const int* __restrict__ ekey,
    int* __restrict__ cursor, int* __restrict__ esrc)
{
  int e = blockIdx.x * 256 + threadIdx.x;
  if (e >= E_EDGES) return;
  int pos = atomicAdd(&cursor[ekey[e]], 1);
  esrc[pos] = ei[e];
}

extern "C" void kernel_launch(void* const* d_in, const int* in_sizes, int n_in,
                              void* d_out, int out_size, void* d_ws, size_t ws_size,
                              hipStream_t stream) {
  const float* x     = (const float*)d_in[0];
  const int*   ei    = (const int*)d_in[1];
  const float* eattr = (const float*)d_in[2];
  const float* lin_w = (const float*)d_in[3];
  const float* lin_b = (const float*)d_in[4];
  const float* gnn_w = (const float*)d_in[5];
  const float* w_ih  = (const float*)d_in[6];
  const float* w_hh  = (const float*)d_in[7];
  const float* b_ih  = (const float*)d_in[8];
  const float* b_hh  = (const float*)d_in[9];
  const float* mu_w  = (const float*)d_in[10];
  const float* mu_b  = (const float*)d_in[11];
  const float* lv_w  = (const float*)d_in[12];
  const float* lv_b  = (const float*)d_in[13];

  char* ws = (char*)d_ws;
  size_t off = 0;
  ushort* x0b = (ushort*)(ws + off); off += (size_t)N_NODES * L * 2;        // 12.8MB
  ushort* ghb = (ushort*)(ws + off); off += (size_t)N_NODES * 3 * L * 2;    // 38.4MB
  ushort* m_a = (ushort*)(ws + off); off += (size_t)N_NODES * L * 2;        // 12.8MB
  ushort* m_b = (ushort*)(ws + off); off += (size_t)N_NODES * L * 2;        // 12.8MB
  ushort* wsb = (ushort*)(ws + off); off += (size_t)WTOT * 2;               // 0.66MB
  int* counts  = (int*)(ws + off); off += (NB4 + 1024) * 4;
  int* excl    = (int*)(ws + off); off += (NB4 + 1024) * 4;
  int* offs4   = (int*)(ws + off); off += (NB4 + 1024) * 4;
  int* cursor4 = (int*)(ws + off); off += (NB4 + 1024) * 4;
  int* bsum    = (int*)(ws + off); off += 256 * 4;
  int* boff    = (int*)(ws + off); off += 256 * 4;
  int* ekey    = (int*)(ws + off); off += (size_t)E_EDGES * 4;
  int* esrc    = (int*)(ws + off); off += (size_t)E_EDGES * 4;

  dim3 blk(256);
  const int GEMM_GRID = (N_NODES + 127) / 128;   // 391 (gh, heads)
  const int STEP_GRID = (N_NODES + 15) / 16;     // 3125
  const int NSB = (NB4 + 1023) / 1024;           // 196

  convert_weights<<<(WTOT + 255) / 256, blk, 0, stream>>>(
      w_hh, w_ih, gnn_w, mu_w, lv_w, wsb);

  // CSR keyed by (dst*4+type), constant across steps
  hipMemsetAsync(counts, 0, NB4 * sizeof(int), stream);
  hist_key<<<(E_EDGES + 255) / 256, blk, 0, stream>>>(ei, eattr, counts, ekey);
  scan_block<<<NSB, 1024, 0, stream>>>(counts, excl, bsum, NB4);
  scan_bsums<<<1, 256, 0, stream>>>(bsum, boff, NSB);
  scan_final<<<NSB, 1024, 0, stream>>>(excl, boff, offs4, cursor4, NB4);
  fill_csr<<<(E_EDGES + 255) / 256, blk, 0, stream>>>(ei, ekey, cursor4, esrc);

  // x0 = relu(x @ lin_w^T + lin_b) -> bf16
  dim3 g_x0((N_NODES + BN - 1) / BN, L / BO);
  matmul_x0<<<g_x0, blk, 0, stream>>>(x, lin_w, lin_b, x0b, N_NODES, IN_F, L);

  // gh = x0 @ w_hh^T + b_hh -> bf16
  gemm_mfma<384, 0><<<GEMM_GRID, blk, 0, stream>>>(
      x0b, wsb + WOFF_WHH, b_hh, nullptr, ghb, nullptr, nullptr, N_NODES);

  // fused per-step kernels with m double-buffering
  const ushort* mcur = x0b;
  ushort* mdst = m_a;
  for (int s = 0; s < STEPS; ++s) {
    step_fused<<<STEP_GRID, blk, 0, stream>>>(
        mcur, offs4, esrc, wsb + WOFF_WG + (size_t)s * 65536,
        wsb + WOFF_WIH, b_ih, ghb, x0b, mdst, N_NODES);
    mcur = mdst;
    mdst = (mdst == m_a) ? m_b : m_a;
  }

  float* mu = (float*)d_out;
  float* lv = (float*)d_out + (size_t)N_NODES * L;
  gemm_mfma<256, 4><<<GEMM_GRID, blk, 0, stream>>>(
      mcur, wsb + WOFF_HEADS, mu_b, mu, nullptr, lv_b, lv, N_NODES);
}

// Round 12
// 546.997 us; speedup vs baseline: 1.6649x; 1.0748x over previous
//
#include <hip/hip_runtime.h>
#include <hip/hip_bf16.h>
#include <cmath>

#define N_NODES 50000
#define IN_F 64
#define L 128
#define STEPS 3
#define T_TYPES 4
#define E_EDGES 800000
#define NB4 (N_NODES * 4)

typedef __attribute__((ext_vector_type(8))) __bf16 bf16x8_t;
typedef __attribute__((ext_vector_type(4))) float f32x4;

__device__ inline float bf2f(ushort u) {
  union { uint i; float f; } v; v.i = ((uint)u) << 16; return v.f;
}
__device__ inline ushort f2bf(float f) {
  union { float f; uint u; } v; v.f = f;
  uint u = v.u;
  u += 0x7fffu + ((u >> 16) & 1u);  // RNE
  return (ushort)(u >> 16);
}

// ---------------- fp32 tiled matmul for x0 (K=64), writes bf16 ----------------
#define BN 64
#define BO 64
#define BK 16
__global__ __launch_bounds__(256) void matmul_x0(
    const float* __restrict__ A, const float* __restrict__ W,
    const float* __restrict__ bias, ushort* __restrict__ Cb,
    int N, int K, int OUT)
{
  __shared__ float As[BN][BK + 1];
  __shared__ float Ws[BO][BK + 1];
  const int tid = threadIdx.x;
  const int n_base = blockIdx.x * BN;
  const int o_base = blockIdx.y * BO;
  const int tx = tid & 15, ty = tid >> 4;
  const int n0 = ty * 4, o0 = tx * 4;
  const int lr = tid >> 2, lc = (tid & 3) * 4;
  float acc[4][4] = {{0.f, 0.f, 0.f, 0.f}};
  for (int kc = 0; kc < K; kc += BK) {
    int gn = n_base + lr;
    float4 av = make_float4(0.f, 0.f, 0.f, 0.f);
    if (gn < N) av = *(const float4*)(A + (size_t)gn * K + kc + lc);
    As[lr][lc + 0] = av.x; As[lr][lc + 1] = av.y;
    As[lr][lc + 2] = av.z; As[lr][lc + 3] = av.w;
    float4 wv = *(const float4*)(W + (size_t)(o_base + lr) * K + kc + lc);
    Ws[lr][lc + 0] = wv.x; Ws[lr][lc + 1] = wv.y;
    Ws[lr][lc + 2] = wv.z; Ws[lr][lc + 3] = wv.w;
    __syncthreads();
#pragma unroll
    for (int kk = 0; kk < BK; ++kk) {
      float a[4], w[4];
#pragma unroll
      for (int i = 0; i < 4; ++i) a[i] = As[n0 + i][kk];
#pragma unroll
      for (int j = 0; j < 4; ++j) w[j] = Ws[o0 + j][kk];
#pragma unroll
      for (int i = 0; i < 4; ++i)
#pragma unroll
        for (int j = 0; j < 4; ++j) acc[i][j] += a[i] * w[j];
    }
    __syncthreads();
  }
#pragma unroll
  for (int i = 0; i < 4; ++i) {
    int gn = n_base + n0 + i;
    if (gn >= N) continue;
    int o = o_base + o0;
    float v0 = fmaxf(acc[i][0] + bias[o + 0], 0.f);
    float v1 = fmaxf(acc[i][1] + bias[o + 1], 0.f);
    float v2 = fmaxf(acc[i][2] + bias[o + 2], 0.f);
    float v3 = fmaxf(acc[i][3] + bias[o + 3], 0.f);
    uint2 pk;
    pk.x = (uint)f2bf(v0) | ((uint)f2bf(v1) << 16);
    pk.y = (uint)f2bf(v2) | ((uint)f2bf(v3) << 16);
    *(uint2*)(Cb + (size_t)gn * OUT + o) = pk;
  }
}

// ---------------- MFMA GEMM (K=128): KIND 0: bf16+bias (gh). KIND 4: heads mu/lv f32 ----------------
template<int OUT, int KIND>
__global__ __launch_bounds__(256) void gemm_mfma(
    const ushort* __restrict__ A, const ushort* __restrict__ W,
    const float* __restrict__ bias, float* __restrict__ Cf,
    ushort* __restrict__ Cb, const float* __restrict__ bias2,
    float* __restrict__ Cf2, int N)
{
  constexpr int K = 128;
  constexpr int NOT = OUT / 16;
  const int lane = threadIdx.x & 63;
  const int wave = threadIdx.x >> 6;
  const int r = lane & 15;
  const int kg = lane >> 4;
  const int row0 = (blockIdx.x * 8 + wave * 2) * 16;
  if (row0 >= N) return;

  int arow0 = row0 + r;          if (arow0 >= N) arow0 = N - 1;
  int arow1 = row0 + 16 + r;     if (arow1 >= N) arow1 = N - 1;
  const ushort* ap0 = A + (size_t)arow0 * K + kg * 8;
  const ushort* ap1 = A + (size_t)arow1 * K + kg * 8;
  const ushort* wp = W + (size_t)r * K + kg * 8;

  bf16x8_t af[2][4];
#pragma unroll
  for (int kt = 0; kt < 4; ++kt) {
    af[0][kt] = *(const bf16x8_t*)(ap0 + kt * 32);
    af[1][kt] = *(const bf16x8_t*)(ap1 + kt * 32);
  }
#pragma unroll
  for (int otp = 0; otp < NOT / 2; ++otp) {
    bf16x8_t w0[4], w1[4];
#pragma unroll
    for (int kt = 0; kt < 4; ++kt) {
      w0[kt] = *(const bf16x8_t*)(wp + (size_t)(2 * otp) * 16 * K + kt * 32);
      w1[kt] = *(const bf16x8_t*)(wp + (size_t)(2 * otp + 1) * 16 * K + kt * 32);
    }
    f32x4 acc[2][2] = {{{0.f,0.f,0.f,0.f},{0.f,0.f,0.f,0.f}},
                       {{0.f,0.f,0.f,0.f},{0.f,0.f,0.f,0.f}}};
#pragma unroll
    for (int kt = 0; kt < 4; ++kt) {
#pragma unroll
      for (int rt = 0; rt < 2; ++rt) {
        acc[rt][0] = __builtin_amdgcn_mfma_f32_16x16x32_bf16(af[rt][kt], w0[kt], acc[rt][0], 0, 0, 0);
        acc[rt][1] = __builtin_amdgcn_mfma_f32_16x16x32_bf16(af[rt][kt], w1[kt], acc[rt][1], 0, 0, 0);
      }
    }
#pragma unroll
    for (int rt = 0; rt < 2; ++rt) {
#pragma unroll
      for (int oi = 0; oi < 2; ++oi) {
        int o = (2 * otp + oi) * 16 + r;
#pragma unroll
        for (int reg = 0; reg < 4; ++reg) {
          int n = row0 + rt * 16 + kg * 4 + reg;
          if (n >= N) continue;
          float v = acc[rt][oi][reg];
          if constexpr (KIND == 0) {
            Cb[(size_t)n * OUT + o] = f2bf(v + bias[o]);
          } else {
            if (o < 128) Cf[(size_t)n * 128 + o] = v + bias[o];
            else Cf2[(size_t)n * 128 + (o - 128)] = v + bias2[o - 128];
          }
        }
      }
    }
  }
}

// ---------------- fused step: gather->LDS, sgemm->LDS, GRU->m_out ----------------
// block = 16 nodes, 4 waves. s_lds[16][512] and a_lds[16][128] XOR-swizzled:
// byte ^= ((row&7)<<4) so column-slice b128 reads hit 8 distinct 16B slots (2-way, free).
// Gather: unroll-8 over the node's WHOLE edge range; type routing via wave-uniform
// branches (j vs b1/b2/b3, all scalar) -> 8 independent row loads in flight, no shfl.
__global__ __launch_bounds__(256) void step_fused(
    const ushort* __restrict__ m, const int* __restrict__ offs4,
    const int* __restrict__ esrc, const ushort* __restrict__ Wg,
    const ushort* __restrict__ Wih, const float* __restrict__ bias,
    const ushort* __restrict__ ghb, const ushort* __restrict__ x0b,
    ushort* __restrict__ m_out, int N)
{
  __shared__ ushort s_lds[16 * 512];   // 16KB
  __shared__ ushort a_lds[16 * 128];   // 4KB
  const int tid = threadIdx.x;
  const int lane = tid & 63;
  const int wave = tid >> 6;
  const int node0 = blockIdx.x * 16;

  // ---- phase 1: gather; wave handles 4 nodes ----
  {
    const int ch = lane * 2;
#pragma unroll
    for (int i = 0; i < 4; ++i) {
      const int row = wave * 4 + i;
      const int node = node0 + row;
      const int b0 = __builtin_amdgcn_readfirstlane(offs4[node * 4 + 0]);
      const int b1 = __builtin_amdgcn_readfirstlane(offs4[node * 4 + 1]);
      const int b2 = __builtin_amdgcn_readfirstlane(offs4[node * 4 + 2]);
      const int b3 = __builtin_amdgcn_readfirstlane(offs4[node * 4 + 3]);
      const int b4 = __builtin_amdgcn_readfirstlane(offs4[node * 4 + 4]);
      float a0x = 0.f, a0y = 0.f, a1x = 0.f, a1y = 0.f;
      float a2x = 0.f, a2y = 0.f, a3x = 0.f, a3y = 0.f;

#define ACCUM(hv, jj)                                                 \
      { float lo_ = bf2f((ushort)((hv) & 0xffff));                    \
        float hi_ = bf2f((ushort)((hv) >> 16));                       \
        if ((jj) < b1)      { a0x += lo_; a0y += hi_; }               \
        else if ((jj) < b2) { a1x += lo_; a1y += hi_; }               \
        else if ((jj) < b3) { a2x += lo_; a2y += hi_; }               \
        else                { a3x += lo_; a3y += hi_; } }

      int j = b0;
      for (; j + 7 < b4; j += 8) {
        int s0 = esrc[j + 0], s1 = esrc[j + 1], s2 = esrc[j + 2], s3 = esrc[j + 3];
        int s4 = esrc[j + 4], s5 = esrc[j + 5], s6 = esrc[j + 6], s7 = esrc[j + 7];
        uint h0 = *(const uint*)(m + (size_t)s0 * 128 + ch);
        uint h1 = *(const uint*)(m + (size_t)s1 * 128 + ch);
        uint h2 = *(const uint*)(m + (size_t)s2 * 128 + ch);
        uint h3 = *(const uint*)(m + (size_t)s3 * 128 + ch);
        uint h4 = *(const uint*)(m + (size_t)s4 * 128 + ch);
        uint h5 = *(const uint*)(m + (size_t)s5 * 128 + ch);
        uint h6 = *(const uint*)(m + (size_t)s6 * 128 + ch);
        uint h7 = *(const uint*)(m + (size_t)s7 * 128 + ch);
        ACCUM(h0, j + 0) ACCUM(h1, j + 1) ACCUM(h2, j + 2) ACCUM(h3, j + 3)
        ACCUM(h4, j + 4) ACCUM(h5, j + 5) ACCUM(h6, j + 6) ACCUM(h7, j + 7)
      }
      for (; j + 1 < b4; j += 2) {
        int s0 = esrc[j + 0], s1 = esrc[j + 1];
        uint h0 = *(const uint*)(m + (size_t)s0 * 128 + ch);
        uint h1 = *(const uint*)(m + (size_t)s1 * 128 + ch);
        ACCUM(h0, j + 0) ACCUM(h1, j + 1)
      }
      if (j < b4) {
        int s0 = esrc[j];
        uint h0 = *(const uint*)(m + (size_t)s0 * 128 + ch);
        ACCUM(h0, j)
      }
#undef ACCUM

      char* srow = (char*)s_lds + row * 1024;
      const int swz = (row & 7) << 4;
      *(uint*)(srow + ((0 * 256 + lane * 4) ^ swz)) = (uint)f2bf(a0x) | ((uint)f2bf(a0y) << 16);
      *(uint*)(srow + ((1 * 256 + lane * 4) ^ swz)) = (uint)f2bf(a1x) | ((uint)f2bf(a1y) << 16);
      *(uint*)(srow + ((2 * 256 + lane * 4) ^ swz)) = (uint)f2bf(a2x) | ((uint)f2bf(a2y) << 16);
      *(uint*)(srow + ((3 * 256 + lane * 4) ^ swz)) = (uint)f2bf(a3x) | ((uint)f2bf(a3y) << 16);
    }
  }
  __syncthreads();

  const int r = lane & 15;
  const int kg = lane >> 4;
  const int rswz = (r & 7) << 4;

  // ---- phase 2: agg = S @ Wg^T (K=512); wave owns out cols [wave*32, wave*32+32) ----
  {
    const ushort* wp = Wg + (size_t)(wave * 32 + r) * 512 + kg * 8;
    f32x4 acc0 = {0.f,0.f,0.f,0.f}, acc1 = {0.f,0.f,0.f,0.f};
#pragma unroll
    for (int kt = 0; kt < 16; ++kt) {
      bf16x8_t w0 = *(const bf16x8_t*)(wp + kt * 32);
      bf16x8_t w1 = *(const bf16x8_t*)(wp + (size_t)16 * 512 + kt * 32);
      bf16x8_t af = *(const bf16x8_t*)((const char*)s_lds +
                      ((r * 1024 + kg * 16 + kt * 64) ^ rswz));
      acc0 = __builtin_amdgcn_mfma_f32_16x16x32_bf16(af, w0, acc0, 0, 0, 0);
      acc1 = __builtin_amdgcn_mfma_f32_16x16x32_bf16(af, w1, acc1, 0, 0, 0);
    }
#pragma unroll
    for (int reg = 0; reg < 4; ++reg) {
      int row = kg * 4 + reg;
      int sw = (row & 7) << 4;
      *(ushort*)((char*)a_lds + ((row * 256 + (wave * 32 + r) * 2) ^ sw)) = f2bf(acc0[reg]);
      *(ushort*)((char*)a_lds + ((row * 256 + (wave * 32 + 16 + r) * 2) ^ sw)) = f2bf(acc1[reg]);
    }
  }
  __syncthreads();

  // ---- phase 3: gi = agg @ w_ih^T (K=128) + GRU epilogue; wave owns jg={wave,wave+4} ----
  bf16x8_t af2[4];
#pragma unroll
  for (int kt = 0; kt < 4; ++kt)
    af2[kt] = *(const bf16x8_t*)((const char*)a_lds +
                ((r * 256 + kg * 16 + kt * 64) ^ rswz));

#pragma unroll
  for (int jl = 0; jl < 2; ++jl) {
    const int jg = wave + jl * 4;
    const ushort* wr = Wih + ((size_t)(0 * 128 + jg * 16 + r)) * 128 + kg * 8;
    const ushort* wz = Wih + ((size_t)(1 * 128 + jg * 16 + r)) * 128 + kg * 8;
    const ushort* wn = Wih + ((size_t)(2 * 128 + jg * 16 + r)) * 128 + kg * 8;
    f32x4 ar = {0.f,0.f,0.f,0.f}, az = {0.f,0.f,0.f,0.f}, an = {0.f,0.f,0.f,0.f};
#pragma unroll
    for (int kt = 0; kt < 4; ++kt) {
      bf16x8_t vr = *(const bf16x8_t*)(wr + kt * 32);
      bf16x8_t vz = *(const bf16x8_t*)(wz + kt * 32);
      bf16x8_t vn = *(const bf16x8_t*)(wn + kt * 32);
      ar = __builtin_amdgcn_mfma_f32_16x16x32_bf16(af2[kt], vr, ar, 0, 0, 0);
      az = __builtin_amdgcn_mfma_f32_16x16x32_bf16(af2[kt], vz, az, 0, 0, 0);
      an = __builtin_amdgcn_mfma_f32_16x16x32_bf16(af2[kt], vn, an, 0, 0, 0);
    }
    const int j = jg * 16 + r;
    const float br = bias[j], bz = bias[128 + j], bn = bias[256 + j];
#pragma unroll
    for (int reg = 0; reg < 4; ++reg) {
      int n = node0 + kg * 4 + reg;
      if (n >= N) continue;
      const ushort* ghp = ghb + (size_t)n * 384;
      float gir = ar[reg] + br + bf2f(ghp[j]);
      float giz = az[reg] + bz + bf2f(ghp[128 + j]);
      float ghn = bf2f(ghp[256 + j]);
      float rr = 1.f / (1.f + expf(-gir));
      float zz = 1.f / (1.f + expf(-giz));
      float nn = tanhf(an[reg] + bn + rr * ghn);
      float x0v = bf2f(x0b[(size_t)n * 128 + j]);
      float h = (1.f - zz) * nn + zz * x0v;
      m_out[(size_t)n * 128 + j] = f2bf(fmaxf(h, 0.f));
    }
  }
}

// ---------------- weight conversion f32 -> bf16 (packed segments) ----------------
// Wg[s][c][t*128+j] = 2 * gnn_w[s][t][c][j]
#define WOFF_WHH 0
#define WOFF_WIH 49152
#define WOFF_WG 98304
#define WOFF_HEADS 294912
#define WTOT 327680

__global__ __launch_bounds__(256) void convert_weights(
    const float* __restrict__ w_hh, const float* __restrict__ w_ih,
    const float* __restrict__ gnn_w, const float* __restrict__ mu_w,
    const float* __restrict__ lv_w, ushort* __restrict__ wsb)
{
  int i = blockIdx.x * 256 + threadIdx.x;
  if (i >= WTOT) return;
  float v;
  if (i < WOFF_WIH) v = w_hh[i];
  else if (i < WOFF_WG) v = w_ih[i - WOFF_WIH];
  else if (i < WOFF_HEADS) {
    int k = i - WOFF_WG;
    int s = k >> 16;
    int rr = k & 65535;
    int c = rr >> 9;
    int col = rr & 511;
    int t = col >> 7;
    int j = col & 127;
    v = 2.f * gnn_w[(((size_t)s * 4 + t) * 128 + c) * 128 + j];
  } else {
    int k = i - WOFF_HEADS;
    v = (k < 16384) ? mu_w[k] : lv_w[k - 16384];
  }
  wsb[i] = f2bf(v);
}

// ---------------- CSR build keyed by (dst*4 + type) ----------------
__global__ __launch_bounds__(256) void hist_key(
    const int* __restrict__ ei, const float* __restrict__ ea,
    int* __restrict__ counts, int* __restrict__ ekey)
{
  int e = blockIdx.x * 256 + threadIdx.x;
  if (e >= E_EDGES) return;
  const float* a = ea + (size_t)e * T_TYPES;
  float bv = a[0]; int bi = 0;
#pragma unroll
  for (int t = 1; t < T_TYPES; ++t) {
    float v = a[t];
    if (v > bv) { bv = v; bi = t; }
  }
  int key = ei[E_EDGES + e] * 4 + bi;
  ekey[e] = key;
  atomicAdd(&counts[key], 1);
}

__global__ __launch_bounds__(1024) void scan_block(
    const int* __restrict__ counts, int* __restrict__ excl,
    int* __restrict__ bsum, int n)
{
  __shared__ int ls[1024];
  const int tid = threadIdx.x;
  const int i = blockIdx.x * 1024 + tid;
  int v = (i < n) ? counts[i] : 0;
  ls[tid] = v;
  __syncthreads();
  for (int off = 1; off < 1024; off <<= 1) {
    int t = (tid >= off) ? ls[tid - off] : 0;
    __syncthreads();
    ls[tid] += t;
    __syncthreads();
  }
  if (i < n) excl[i] = ls[tid] - v;
  if (tid == 1023) bsum[blockIdx.x] = ls[1023];
}

__global__ __launch_bounds__(256) void scan_bsums(
    const int* __restrict__ bsum, int* __restrict__ boff, int nb)
{
  __shared__ int ls[256];
  const int tid = threadIdx.x;
  int v = (tid < nb) ? bsum[tid] : 0;
  ls[tid] = v;
  __syncthreads();
  for (int off = 1; off < 256; off <<= 1) {
    int t = (tid >= off) ? ls[tid - off] : 0;
    __syncthreads();
    ls[tid] += t;
    __syncthreads();
  }
  if (tid < nb) boff[tid] = ls[tid] - v;
}

__global__ __launch_bounds__(1024) void scan_final(
    const int* __restrict__ excl, const int* __restrict__ boff,
    int* __restrict__ offsets, int* __restrict__ cursor, int n)
{
  int i = blockIdx.x * 1024 + threadIdx.x;
  if (i == 0) { offsets[n] = E_EDGES; }
  if (i >= n) return;
  int o = excl[i] + boff[blockIdx.x];
  offsets[i] = o;
  cursor[i] = o;
}

__global__ __launch_bounds__(256) void fill_csr(
    const int* __restrict__ ei, const int* __restrict__ ekey,
    int* __restrict__ cursor, int* __restrict__ esrc)
{
  int e = blockIdx.x * 256 + threadIdx.x;
  if (e >= E_EDGES) return;
  int pos = atomicAdd(&cursor[ekey[e]], 1);
  esrc[pos] = ei[e];
}

extern "C" void kernel_launch(void* const* d_in, const int* in_sizes, int n_in,
                              void* d_out, int out_size, void* d_ws, size_t ws_size,
                              hipStream_t stream) {
  const float* x     = (const float*)d_in[0];
  const int*   ei    = (const int*)d_in[1];
  const float* eattr = (const float*)d_in[2];
  const float* lin_w = (const float*)d_in[3];
  const float* lin_b = (const float*)d_in[4];
  const float* gnn_w = (const float*)d_in[5];
  const float* w_ih  = (const float*)d_in[6];
  const float* w_hh  = (const float*)d_in[7];
  const float* b_ih  = (const float*)d_in[8];
  const float* b_hh  = (const float*)d_in[9];
  const float* mu_w  = (const float*)d_in[10];
  const float* mu_b  = (const float*)d_in[11];
  const float* lv_w  = (const float*)d_in[12];
  const float* lv_b  = (const float*)d_in[13];

  char* ws = (char*)d_ws;
  size_t off = 0;
  ushort* x0b = (ushort*)(ws + off); off += (size_t)N_NODES * L * 2;        // 12.8MB
  ushort* ghb = (ushort*)(ws + off); off += (size_t)N_NODES * 3 * L * 2;    // 38.4MB
  ushort* m_a = (ushort*)(ws + off); off += (size_t)N_NODES * L * 2;        // 12.8MB
  ushort* m_b = (ushort*)(ws + off); off += (size_t)N_NODES * L * 2;        // 12.8MB
  ushort* wsb = (ushort*)(ws + off); off += (size_t)WTOT * 2;               // 0.66MB
  int* counts  = (int*)(ws + off); off += (NB4 + 1024) * 4;
  int* excl    = (int*)(ws + off); off += (NB4 + 1024) * 4;
  int* offs4   = (int*)(ws + off); off += (NB4 + 1024) * 4;
  int* cursor4 = (int*)(ws + off); off += (NB4 + 1024) * 4;
  int* bsum    = (int*)(ws + off); off += 256 * 4;
  int* boff    = (int*)(ws + off); off += 256 * 4;
  int* ekey    = (int*)(ws + off); off += (size_t)E_EDGES * 4;
  int* esrc    = (int*)(ws + off); off += (size_t)E_EDGES * 4;

  dim3 blk(256);
  const int GEMM_GRID = (N_NODES + 127) / 128;   // 391 (gh, heads)
  const int STEP_GRID = (N_NODES + 15) / 16;     // 3125
  const int NSB = (NB4 + 1023) / 1024;           // 196

  convert_weights<<<(WTOT + 255) / 256, blk, 0, stream>>>(
      w_hh, w_ih, gnn_w, mu_w, lv_w, wsb);

  // CSR keyed by (dst*4+type), constant across steps
  hipMemsetAsync(counts, 0, NB4 * sizeof(int), stream);
  hist_key<<<(E_EDGES + 255) / 256, blk, 0, stream>>>(ei, eattr, counts, ekey);
  scan_block<<<NSB, 1024, 0, stream>>>(counts, excl, bsum, NB4);
  scan_bsums<<<1, 256, 0, stream>>>(bsum, boff, NSB);
  scan_final<<<NSB, 1024, 0, stream>>>(excl, boff, offs4, cursor4, NB4);
  fill_csr<<<(E_EDGES + 255) / 256, blk, 0, stream>>>(ei, ekey, cursor4, esrc);

  // x0 = relu(x @ lin_w^T + lin_b) -> bf16
  dim3 g_x0((N_NODES + BN - 1) / BN, L / BO);
  matmul_x0<<<g_x0, blk, 0, stream>>>(x, lin_w, lin_b, x0b, N_NODES, IN_F, L);

  // gh = x0 @ w_hh^T + b_hh -> bf16
  gemm_mfma<384, 0><<<GEMM_GRID, blk, 0, stream>>>(
      x0b, wsb + WOFF_WHH, b_hh, nullptr, ghb, nullptr, nullptr, N_NODES);

  // fused per-step kernels with m double-buffering
  const ushort* mcur = x0b;
  ushort* mdst = m_a;
  for (int s = 0; s < STEPS; ++s) {
    step_fused<<<STEP_GRID, blk, 0, stream>>>(
        mcur, offs4, esrc, wsb + WOFF_WG + (size_t)s * 65536,
        wsb + WOFF_WIH, b_ih, ghb, x0b, mdst, N_NODES);
    mcur = mdst;
    mdst = (mdst == m_a) ? m_b : m_a;
  }

  float* mu = (float*)d_out;
  float* lv = (float*)d_out + (size_t)N_NODES * L;
  gemm_mfma<256, 4><<<GEMM_GRID, blk, 0, stream>>>(
      mcur, wsb + WOFF_HEADS, mu_b, mu, nullptr, lv_b, lv, N_NODES);
}